// Round 2
// baseline (14036.069 us; speedup 1.0000x reference)
//
#include <hip/hip_runtime.h>
#include <hip/hip_cooperative_groups.h>
#include <math.h>

namespace cg = cooperative_groups;

#define H 512
#define V 50000
#define B 64
#define S 50
#define STEPS 31
#define NBLK 256
#define NTHR 512
#define G4 2048
static const size_t BV = (size_t)B * V;   // 3,200,000

// ---------------- fused-kernel workspace layout (floats) ----------------
#define FO_HT   0          // attended h state  [512][64]  (LSTM input h)
#define FO_CT   32768      // attended c state  [512][64]  (LSTM input c)
#define FO_HRT  65536      // pre-attention h_rnn [512][64]
#define FO_CRT  98304      // pre-attention c_rnn [512][64]
#define FO_SLOT 131072     // 2 x 64 u64 argmax slots (=256 floats), double-buffered

// ---------------- fallback (previous verified) ws layout ----------------
#define OFF_XT   0
#define OFF_HT   32768
#define OFF_CT   65536
#define OFF_HRT  98304
#define OFF_CRT  131072
#define OFF_TOK  163840
#define OFF_GP   163904

// =====================================================================
// Fused persistent cooperative kernel
// =====================================================================

__device__ __forceinline__ unsigned sortable_bits(float f) {
    unsigned u = __float_as_uint(f);
    return (u & 0x80000000u) ? ~u : (u | 0x80000000u);
}

__device__ __forceinline__ unsigned long long shfl_down_u64(unsigned long long x, int off) {
    const unsigned lo = __shfl_down((unsigned)x, off);
    const unsigned hi = __shfl_down((unsigned)(x >> 32), off);
    return (((unsigned long long)hi) << 32) | (unsigned long long)lo;
}

__global__ __launch_bounds__(NTHR, 2) void kfused(
    const float* __restrict__ E,   const float* __restrict__ fcb,
    const float* __restrict__ Wih, const float* __restrict__ Whh,
    const float* __restrict__ bih, const float* __restrict__ bhh,
    const float* __restrict__ enc, const float* __restrict__ h0,
    const float* __restrict__ c0,  const int* __restrict__ tok0,
    float* __restrict__ out,       float* __restrict__ ws)
{
    cg::grid_group grid = cg::this_grid();
    const int bid  = blockIdx.x;
    const int tid  = threadIdx.x;
    const int lane = tid & 63;
    unsigned long long* slotbuf = (unsigned long long*)(ws + FO_SLOT); // [2][64]

    __shared__ float gates_lds[16][64];
    __shared__ float sc_h[64], sc_c[64], a_h[64], a_c[64];

    // ---------------- P0: init state, zero both slot buffers ----------------
    {
        const int g = bid * NTHR + tid;
        if (g < H * B) {
            const int k = g >> 6, b = g & 63;
            ws[FO_HT + k * 64 + b] = h0[(size_t)b * H + k];
            ws[FO_CT + k * 64 + b] = c0[(size_t)b * H + k];
        }
        if (bid == 0 && tid < 128) slotbuf[tid] = 0ull;
    }
    grid.sync();

    for (int t = 0; t < STEPS; ++t) {
        // ================= P1: gates (full-K) + fused LSTM finalize =================
        // 128 blocks; block owns cells m = bid*4 .. bid*4+3 (all 4 gate rows each).
        // 16 rows/block = 8 waves x 2 rows; lanes = batch.
        // x read directly from E via prev token (no xT materialization).
        if (bid < 128) {
            const int w = __builtin_amdgcn_readfirstlane(tid >> 6); // wave 0..7

            int tk;
            if (t == 0) tk = tok0[lane];
            else tk = (int)(0xFFFFFFFFu -
                     (unsigned)(slotbuf[((t - 1) & 1) * 64 + lane] & 0xFFFFFFFFull));
            const float4* xp4 = (const float4*)(E + (size_t)tk * H);

            const float* wip[2];
            const float* whp[2];
#pragma unroll
            for (int i = 0; i < 2; ++i) {
                const int r = w * 2 + i;                 // 0..15  (gate = r>>2, mloc = r&3)
                const int j = (r >> 2) * 512 + bid * 4 + (r & 3);
                wip[i] = Wih + (size_t)j * H;
                whp[i] = Whh + (size_t)j * H;
            }
            float acc[2];
#pragma unroll
            for (int i = 0; i < 2; ++i) acc[i] = 0.f;

            for (int k4 = 0; k4 < 128; ++k4) {
                float4 wiv[2], whv[2];
#pragma unroll
                for (int i = 0; i < 2; ++i) {
                    wiv[i] = ((const float4*)wip[i])[k4];
                    whv[i] = ((const float4*)whp[i])[k4];
                }
                const float4 xv4 = xp4[k4];
#pragma unroll
                for (int jj = 0; jj < 4; ++jj) {
                    const int k = k4 * 4 + jj;
                    const float xv = ((const float*)&xv4)[jj];
                    const float hv = ws[FO_HT + k * 64 + lane];
#pragma unroll
                    for (int i = 0; i < 2; ++i)
                        acc[i] += ((const float*)&wiv[i])[jj] * xv
                                + ((const float*)&whv[i])[jj] * hv;
                }
            }
#pragma unroll
            for (int i = 0; i < 2; ++i) gates_lds[w * 2 + i][lane] = acc[i];
            __syncthreads();

            // LSTM cell finalize: 256 threads = 4 m x 64 b
            if (tid < 256) {
                const int mloc = tid >> 6;       // 0..3
                const int b = lane;
                float gv[4];
#pragma unroll
                for (int gi = 0; gi < 4; ++gi) {
                    const int j = gi * 512 + bid * 4 + mloc;
                    gv[gi] = bih[j] + bhh[j] + gates_lds[gi * 4 + mloc][b];
                }
                const float ig = 1.f / (1.f + expf(-gv[0]));
                const float fg = 1.f / (1.f + expf(-gv[1]));
                const float gg = tanhf(gv[2]);
                const float og = 1.f / (1.f + expf(-gv[3]));
                const int m = bid * 4 + mloc;
                const float c_prev = ws[FO_CT + m * 64 + b];
                const float c_rnn = fg * c_prev + ig * gg;
                const float h_rnn = og * tanhf(c_rnn);
                ws[FO_CRT + m * 64 + b] = c_rnn;
                ws[FO_HRT + m * 64 + b] = h_rnn;
            }
        }
        // concurrent with P1: token writeback for step t-1, reset current slot buffer
        if (bid == NBLK - 1) {
            if (tid < 64) slotbuf[(t & 1) * 64 + tid] = 0ull;      // will hold step t winners
            if (tid >= 64 && tid < 128 && t > 0) {
                const int b = tid - 64;
                const unsigned long long key = slotbuf[((t - 1) & 1) * 64 + b];
                const int tk = (int)(0xFFFFFFFFu - (unsigned)(key & 0xFFFFFFFFull));
                out[(size_t)STEPS * BV + (size_t)b * STEPS + (t - 1)] = (float)tk;
            }
        }
        grid.sync();

        // ================= P3: logits + fused argmax (+ attention) =================
        // 782 chunks of 64 vocab rows; each block does {bid, bid+256, bid+512};
        // the 14 leftover chunks are split in batch-halves over blocks 0..27.
        {
            const int vt = tid & 63;
            const int bg = tid >> 6;          // 0..7 -> 8 batches each
            const int b0 = bg * 8;
            const float* __restrict__ hrow = ws + FO_HRT + b0;
            unsigned long long best[8];
#pragma unroll
            for (int i = 0; i < 8; ++i) best[i] = 0ull;

#pragma unroll 1
            for (int ci = 0; ci < 4; ++ci) {
                if (ci == 3 && !(bid < 28 && ((bg >> 2) == (bid & 1)))) break;
                const int c = (ci < 3) ? (bid + ci * 256) : (768 + (bid >> 1));
                const int v = c * 64 + vt;
                const int vc = (v < V) ? v : 0;
                float acc[8];
#pragma unroll
                for (int i = 0; i < 8; ++i) acc[i] = 0.f;
                const float4* e4 = (const float4*)(E + (size_t)vc * H);
                for (int k4 = 0; k4 < 128; ++k4) {
                    const float4 e = e4[k4];
#pragma unroll
                    for (int jj = 0; jj < 4; ++jj) {
                        const float ev = ((const float*)&e)[jj];
                        const float* hr = hrow + (k4 * 4 + jj) * 64;
#pragma unroll
                        for (int bb = 0; bb < 8; ++bb) acc[bb] += ev * hr[bb];
                    }
                }
                if (v < V) {
                    const float bias = fcb[v];
                    float* o = out + (size_t)t * BV + (size_t)b0 * V + v;
                    const unsigned idxkey = 0xFFFFFFFFu - (unsigned)v;
#pragma unroll
                    for (int bb = 0; bb < 8; ++bb) {
                        const float lv = acc[bb] + bias;
                        __builtin_nontemporal_store(lv, o + (size_t)bb * V);
                        const unsigned long long key =
                            (((unsigned long long)sortable_bits(lv)) << 32) |
                            (unsigned long long)idxkey;
                        if (key > best[bb]) best[bb] = key;
                    }
                }
            }
            // per-wave reduce over the 64 row-lanes, then one atomic per batch
#pragma unroll
            for (int off = 32; off; off >>= 1) {
#pragma unroll
                for (int bb = 0; bb < 8; ++bb) {
                    const unsigned long long o2 = shfl_down_u64(best[bb], off);
                    if (o2 > best[bb]) best[bb] = o2;
                }
            }
            if (vt == 0) {
                unsigned long long* scur = slotbuf + (t & 1) * 64;
#pragma unroll
                for (int bb = 0; bb < 8; ++bb) atomicMax(&scur[b0 + bb], best[bb]);
            }
        }
        // attention for batch b = bid-64 (depends only on h_rnn/c_rnn; hides under logits)
        if (bid >= 64 && bid < 128) {
            const int b = bid - 64;
            const int wv = tid >> 6;          // 0..7
            float hr8[8], cr8[8];
#pragma unroll
            for (int i = 0; i < 8; ++i) {
                const int k = lane * 8 + i;
                hr8[i] = ws[FO_HRT + k * 64 + b];
                cr8[i] = ws[FO_CRT + k * 64 + b];
            }
            const float scale = 0.044194173824159216f; // 1/sqrt(512)
            for (int s = wv; s < S; s += 8) {
                const float* e = enc + ((size_t)s * B + b) * H + lane * 8;
                float dh = 0.f, dc = 0.f;
#pragma unroll
                for (int i = 0; i < 8; ++i) { const float ev = e[i]; dh += ev * hr8[i]; dc += ev * cr8[i]; }
#pragma unroll
                for (int off = 32; off; off >>= 1) { dh += __shfl_down(dh, off); dc += __shfl_down(dc, off); }
                if (lane == 0) { sc_h[s] = dh * scale; sc_c[s] = dc * scale; }
            }
            __syncthreads();
            if (wv < 2) {
                float* sc = wv ? sc_c : sc_h;
                float* a  = wv ? a_c  : a_h;
                const float vval = (lane < S) ? sc[lane] : -__builtin_inff();
                float mx = vval;
#pragma unroll
                for (int off = 32; off; off >>= 1) mx = fmaxf(mx, __shfl_xor(mx, off));
                const float e = (lane < S) ? expf(vval - mx) : 0.f;
                float sum = e;
#pragma unroll
                for (int off = 32; off; off >>= 1) sum += __shfl_xor(sum, off);
                if (lane < S) a[lane] = e / sum;
            }
            __syncthreads();
            if (tid < 256) {
                const int kk = tid * 2;
                float ch0 = 0, ch1 = 0, cc0 = 0, cc1 = 0;
                for (int s = 0; s < S; ++s) {
                    const float2 e2 = *(const float2*)(enc + ((size_t)s * B + b) * H + kk);
                    const float ah = a_h[s], ac = a_c[s];
                    ch0 += ah * e2.x; ch1 += ah * e2.y;
                    cc0 += ac * e2.x; cc1 += ac * e2.y;
                }
                const float hr0 = ws[FO_HRT + kk * 64 + b], hr1 = ws[FO_HRT + (kk + 1) * 64 + b];
                const float cr0 = ws[FO_CRT + kk * 64 + b], cr1 = ws[FO_CRT + (kk + 1) * 64 + b];
                ws[FO_HT + kk * 64 + b]       = ch0 + hr0;
                ws[FO_HT + (kk + 1) * 64 + b] = ch1 + hr1;
                ws[FO_CT + kk * 64 + b]       = cc0 + cr0;
                ws[FO_CT + (kk + 1) * 64 + b] = cc1 + cr1;
            }
        }
        grid.sync();
    }
    // final step's tokens
    if (bid == NBLK - 1 && tid < 64) {
        const unsigned long long key = slotbuf[((STEPS - 1) & 1) * 64 + tid];
        const int tk = (int)(0xFFFFFFFFu - (unsigned)(key & 0xFFFFFFFFull));
        out[(size_t)STEPS * BV + (size_t)tid * STEPS + (STEPS - 1)] = (float)tk;
    }
}

// =====================================================================
// Fallback: previous harness-verified 5-kernel path (used only if the
// cooperative launch is rejected by the runtime/capture).
// =====================================================================

__global__ __launch_bounds__(256) void k0_init(const float* __restrict__ E,
                                               const int* __restrict__ tok0,
                                               const float* __restrict__ h0,
                                               const float* __restrict__ c0,
                                               float* __restrict__ ws) {
    const int b = blockIdx.x;
    const int t = tok0[b];
    for (int k = threadIdx.x; k < H; k += 256) {
        ws[OFF_XT + k * 64 + b] = E[(size_t)t * H + k];
        ws[OFF_HT + k * 64 + b] = h0[b * H + k];
        ws[OFF_CT + k * 64 + b] = c0[b * H + k];
    }
}

__global__ __launch_bounds__(256) void k1_gates(const float* __restrict__ Wih,
                                                const float* __restrict__ Whh,
                                                float* __restrict__ ws) {
    const int tid = threadIdx.x;
    const int jt = blockIdx.x & 15;
    const int ks = blockIdx.x >> 4;
    const int jl = tid & 127;
    const int bg = __builtin_amdgcn_readfirstlane(tid >> 7);
    const int j = jt * 128 + jl;
    const int b0 = bg * 32;
    const float* __restrict__ xT = ws + OFF_XT;
    const float* __restrict__ hT = ws + OFF_HT;

    float acc[32];
#pragma unroll
    for (int i = 0; i < 32; i++) acc[i] = 0.f;

    const int k0 = ks * 64;
    const float4* wi4 = (const float4*)(Wih + (size_t)j * H + k0);
    const float4* wh4 = (const float4*)(Whh + (size_t)j * H + k0);
    for (int k4 = 0; k4 < 16; k4++) {
        float4 wi = wi4[k4];
        float4 wh = wh4[k4];
#pragma unroll
        for (int jj = 0; jj < 4; jj++) {
            const float wiv = ((const float*)&wi)[jj];
            const float whv = ((const float*)&wh)[jj];
            const int k = k0 + k4 * 4 + jj;
            const float* xr = xT + k * 64 + b0;
            const float* hr = hT + k * 64 + b0;
#pragma unroll
            for (int bb = 0; bb < 32; bb++)
                acc[bb] += wiv * xr[bb] + whv * hr[bb];
        }
    }
    float* outp = ws + OFF_GP + ((size_t)ks * G4 + j) * 64 + b0;
#pragma unroll
    for (int b4 = 0; b4 < 8; b4++)
        ((float4*)outp)[b4] = make_float4(acc[b4*4], acc[b4*4+1], acc[b4*4+2], acc[b4*4+3]);
}

__global__ __launch_bounds__(256) void k2_fin(const float* __restrict__ b_ih,
                                              const float* __restrict__ b_hh,
                                              float* __restrict__ ws) {
    const int tid = threadIdx.x;
    const int b = tid & 63;
    const int m = blockIdx.x * 4 + (tid >> 6);
    const float* __restrict__ gp = ws + OFF_GP;

    float g[4];
#pragma unroll
    for (int gi = 0; gi < 4; gi++) {
        const int j = gi * 512 + m;
        float s = b_ih[j] + b_hh[j];
#pragma unroll
        for (int ks = 0; ks < 8; ks++)
            s += gp[((size_t)ks * G4 + j) * 64 + b];
        g[gi] = s;
    }
    const float ig = 1.f / (1.f + expf(-g[0]));
    const float fg = 1.f / (1.f + expf(-g[1]));
    const float gg = tanhf(g[2]);
    const float og = 1.f / (1.f + expf(-g[3]));
    const float c_prev = ws[OFF_CT + m * 64 + b];
    const float c_rnn = fg * c_prev + ig * gg;
    const float h_rnn = og * tanhf(c_rnn);
    ws[OFF_CRT + m * 64 + b] = c_rnn;
    ws[OFF_HRT + m * 64 + b] = h_rnn;
}

__global__ __launch_bounds__(256) void k3_attn(const float* __restrict__ enc,
                                               float* __restrict__ ws) {
    const int b = blockIdx.x;
    const int tid = threadIdx.x;
    const int lane = tid & 63;
    const int wv = __builtin_amdgcn_readfirstlane(tid >> 6);

    __shared__ float sc_h[64], sc_c[64], a_h[64], a_c[64];

    float hr[8], cr[8];
#pragma unroll
    for (int i = 0; i < 8; i++) {
        const int k = lane * 8 + i;
        hr[i] = ws[OFF_HRT + k * 64 + b];
        cr[i] = ws[OFF_CRT + k * 64 + b];
    }
    const float scale = 0.044194173824159216f;
    for (int s = wv; s < S; s += 4) {
        const float* e = enc + ((size_t)s * B + b) * H + lane * 8;
        float dh = 0.f, dc = 0.f;
#pragma unroll
        for (int i = 0; i < 8; i++) {
            const float ev = e[i];
            dh += ev * hr[i];
            dc += ev * cr[i];
        }
#pragma unroll
        for (int off = 32; off; off >>= 1) {
            dh += __shfl_down(dh, off);
            dc += __shfl_down(dc, off);
        }
        if (lane == 0) { sc_h[s] = dh * scale; sc_c[s] = dc * scale; }
    }
    __syncthreads();
    if (wv < 2) {
        float* sc = wv ? sc_c : sc_h;
        float* a  = wv ? a_c  : a_h;
        float vval = (lane < S) ? sc[lane] : -__builtin_inff();
        float mx = vval;
#pragma unroll
        for (int off = 32; off; off >>= 1) mx = fmaxf(mx, __shfl_xor(mx, off));
        float e = (lane < S) ? expf(vval - mx) : 0.f;
        float sum = e;
#pragma unroll
        for (int off = 32; off; off >>= 1) sum += __shfl_xor(sum, off);
        if (lane < S) a[lane] = e / sum;
    }
    __syncthreads();
    {
        const int kk = tid * 2;
        float ch0 = 0, ch1 = 0, cc0 = 0, cc1 = 0;
        for (int s = 0; s < S; s++) {
            const float2 e2 = *(const float2*)(enc + ((size_t)s * B + b) * H + kk);
            const float ah = a_h[s], ac = a_c[s];
            ch0 += ah * e2.x; ch1 += ah * e2.y;
            cc0 += ac * e2.x; cc1 += ac * e2.y;
        }
        const float hr0 = ws[OFF_HRT + kk * 64 + b], hr1 = ws[OFF_HRT + (kk + 1) * 64 + b];
        const float cr0 = ws[OFF_CRT + kk * 64 + b], cr1 = ws[OFF_CRT + (kk + 1) * 64 + b];
        ws[OFF_HT + kk * 64 + b] = ch0 + hr0;
        ws[OFF_HT + (kk + 1) * 64 + b] = ch1 + hr1;
        ws[OFF_CT + kk * 64 + b] = cc0 + cr0;
        ws[OFF_CT + (kk + 1) * 64 + b] = cc1 + cr1;
    }
}

__global__ __launch_bounds__(256) void k4_logits(const float* __restrict__ E,
                                                 const float* __restrict__ fcb,
                                                 const float* __restrict__ ws,
                                                 float* __restrict__ out,
                                                 int step) {
    const int tid = threadIdx.x;
    const int vt = tid & 127;
    const int bg = __builtin_amdgcn_readfirstlane(tid >> 7);
    const int v = blockIdx.x * 128 + vt;
    const bool valid = v < V;
    const int vc = valid ? v : 0;
    const float* __restrict__ hT = ws + OFF_HRT + bg * 32;

    float acc[32];
#pragma unroll
    for (int i = 0; i < 32; i++) acc[i] = 0.f;

    const float4* e4 = (const float4*)(E + (size_t)vc * H);
    for (int k4 = 0; k4 < 128; k4++) {
        const float4 e = e4[k4];
#pragma unroll
        for (int jj = 0; jj < 4; jj++) {
            const float ev = ((const float*)&e)[jj];
            const float* __restrict__ h = hT + (k4 * 4 + jj) * 64;
#pragma unroll
            for (int bb = 0; bb < 32; bb++) acc[bb] += ev * h[bb];
        }
    }
    if (valid) {
        const float bias = fcb[v];
        float* o = out + (size_t)step * BV + (size_t)(bg * 32) * V + v;
#pragma unroll
        for (int bb = 0; bb < 32; bb++) o[(size_t)bb * V] = acc[bb] + bias;
    }
}

__global__ __launch_bounds__(256) void k5_argmax(const float* __restrict__ E,
                                                 float* __restrict__ ws,
                                                 float* __restrict__ out,
                                                 int step) {
    const int b = blockIdx.x;
    const int tid = threadIdx.x;
    const float* __restrict__ lg = out + (size_t)step * BV + (size_t)b * V;

    float best = -__builtin_inff();
    int bi = 0;
    for (int v = tid; v < V; v += 256) {
        const float x = lg[v];
        if (x > best) { best = x; bi = v; }
    }
#pragma unroll
    for (int off = 32; off; off >>= 1) {
        const float ov = __shfl_down(best, off);
        const int oi = __shfl_down(bi, off);
        if (ov > best || (ov == best && oi < bi)) { best = ov; bi = oi; }
    }
    __shared__ float wvv[4];
    __shared__ int wii[4];
    __shared__ int stok;
    const int lane = tid & 63, w = tid >> 6;
    if (lane == 0) { wvv[w] = best; wii[w] = bi; }
    __syncthreads();
    if (tid == 0) {
        float bv = wvv[0]; int bj = wii[0];
#pragma unroll
        for (int k = 1; k < 4; k++)
            if (wvv[k] > bv || (wvv[k] == bv && wii[k] < bj)) { bv = wvv[k]; bj = wii[k]; }
        stok = bj;
        ((int*)(ws + OFF_TOK))[b] = bj;
        out[(size_t)STEPS * BV + (size_t)b * STEPS + step] = (float)bj;
    }
    __syncthreads();
    const int t = stok;
    for (int k = tid; k < H; k += 256)
        ws[OFF_XT + k * 64 + b] = E[(size_t)t * H + k];
}

// =====================================================================

extern "C" void kernel_launch(void* const* d_in, const int* in_sizes, int n_in,
                              void* d_out, int out_size, void* d_ws, size_t ws_size,
                              hipStream_t stream) {
    (void)in_sizes; (void)n_in; (void)out_size; (void)ws_size;
    const float* E    = (const float*)d_in[0];
    const float* fcb  = (const float*)d_in[1];
    const float* Wih  = (const float*)d_in[2];
    const float* Whh  = (const float*)d_in[3];
    const float* bih  = (const float*)d_in[4];
    const float* bhh  = (const float*)d_in[5];
    const float* enc  = (const float*)d_in[6];
    const float* h0   = (const float*)d_in[7];
    const float* c0   = (const float*)d_in[8];
    const int*   tok0 = (const int*)d_in[9];
    float* out = (float*)d_out;
    float* ws  = (float*)d_ws;

    void* args[12] = { (void*)&E, (void*)&fcb, (void*)&Wih, (void*)&Whh,
                       (void*)&bih, (void*)&bhh, (void*)&enc, (void*)&h0,
                       (void*)&c0, (void*)&tok0, (void*)&out, (void*)&ws };

    hipError_t err = hipLaunchCooperativeKernel((const void*)kfused,
                                                dim3(NBLK), dim3(NTHR),
                                                args, 0, stream);
    if (err != hipSuccess) {
        // Fallback: previously verified multi-kernel path.
        k0_init<<<64, 256, 0, stream>>>(E, tok0, h0, c0, ws);
        for (int t = 0; t < STEPS; t++) {
            k1_gates<<<128, 256, 0, stream>>>(Wih, Whh, ws);
            k2_fin<<<128, 256, 0, stream>>>(bih, bhh, ws);
            k3_attn<<<64, 256, 0, stream>>>(enc, ws);
            k4_logits<<<391, 256, 0, stream>>>(E, fcb, ws, out, t);
            k5_argmax<<<64, 256, 0, stream>>>(E, ws, out, t);
        }
    }
}

// Round 4
// 11566.528 us; speedup vs baseline: 1.2135x; 1.2135x over previous
//
#include <hip/hip_runtime.h>
#include <hip/hip_cooperative_groups.h>
#include <math.h>

namespace cg = cooperative_groups;

#define H 512
#define V 50000
#define B 64
#define S 50
#define STEPS 31
#define NBLK 256
#define NTHR 512
#define G4 2048
static const size_t BV = (size_t)B * V;   // 3,200,000

// ---------------- fused-kernel workspace layout (floats) ----------------
#define FO_HT   0          // attended h state  [512][64]  (LSTM input h)
#define FO_CT   32768      // attended c state  [512][64]  (LSTM input c)
#define FO_HRT  65536      // pre-attention h_rnn [512][64] (attention/residual)
#define FO_CRT  98304      // pre-attention c_rnn [512][64]
#define FO_RED  131072     // per-block argmax partials: 256 blocks x 64 u64 = 32768 floats
#define FO_HR4  163840     // h_rnn quad-packed [128][64][4] = 32768 floats (logits)

// ---------------- fallback (previous verified) ws layout ----------------
#define OFF_XT   0
#define OFF_HT   32768
#define OFF_CT   65536
#define OFF_HRT  98304
#define OFF_CRT  131072
#define OFF_TOK  163840
#define OFF_GP   163904

// =====================================================================
// Fused persistent cooperative kernel
// =====================================================================

__device__ __forceinline__ unsigned sortable_bits(float f) {
    unsigned u = __float_as_uint(f);
    return (u & 0x80000000u) ? ~u : (u | 0x80000000u);
}

__global__ __launch_bounds__(NTHR, 1) void kfused(
    const float* __restrict__ E,   const float* __restrict__ fcb,
    const float* __restrict__ Wih, const float* __restrict__ Whh,
    const float* __restrict__ bih, const float* __restrict__ bhh,
    const float* __restrict__ enc, const float* __restrict__ h0,
    const float* __restrict__ c0,  const int* __restrict__ tok0,
    float* __restrict__ out,       float* __restrict__ ws)
{
    cg::grid_group grid = cg::this_grid();
    const int bid  = blockIdx.x;
    const int tid  = threadIdx.x;
    const int lane = tid & 63;
    const int w    = __builtin_amdgcn_readfirstlane(tid >> 6);  // wave 0..7
    unsigned long long* __restrict__ red = (unsigned long long*)(ws + FO_RED);

    __shared__ float tile_lds[8][32][65];          // 66.5 KB: per-wave logits tiles
    __shared__ float gates_lds[8][64];
    __shared__ unsigned long long redbuf[8][64];
    __shared__ int tok_s[64];
    __shared__ float sc_h[64], sc_c[64], a_h[64], a_c[64];

    // ---------------- P0: init state ----------------
    {
        const int g = bid * NTHR + tid;
        if (g < H * B) {
            const int k = g >> 6, b = g & 63;
            ws[FO_HT + k * 64 + b] = h0[(size_t)b * H + k];
            ws[FO_CT + k * 64 + b] = c0[(size_t)b * H + k];
        }
    }
    grid.sync();

    for (int t = 0; t < STEPS; ++t) {
        // ========== PhaseA: token-reduce (all blocks) + gates/LSTM ==========
        if (t > 0) {
            unsigned long long m = 0;
#pragma unroll 4
            for (int i = 0; i < 32; ++i) {
                const unsigned long long kk = red[(size_t)(w * 32 + i) * 64 + lane];
                if (kk > m) m = kk;
            }
            redbuf[w][lane] = m;
            __syncthreads();
            if (w == 0) {
                unsigned long long mm = redbuf[0][lane];
#pragma unroll
                for (int i = 1; i < 8; ++i) {
                    const unsigned long long kk = redbuf[i][lane];
                    if (kk > mm) mm = kk;
                }
                tok_s[lane] = (int)(0xFFFFFFFFu - (unsigned)(mm & 0xFFFFFFFFull));
            }
            __syncthreads();
        }
        {
            // gates GEMV: block owns cells bid*2, bid*2+1; wave w -> row j (1 row/wave)
            const int tk = (t == 0) ? tok0[lane] : tok_s[lane];
            const int j = (w >> 1) * 512 + bid * 2 + (w & 1);
            const float* __restrict__ wip = Wih + (size_t)j * H;
            const float* __restrict__ whp = Whh + (size_t)j * H;
            const float4* __restrict__ xp4 = (const float4*)(E + (size_t)tk * H);
            float acc = 0.f;
#pragma unroll 2
            for (int k4 = 0; k4 < 128; ++k4) {
                const float4 wi = ((const float4*)wip)[k4];
                const float4 wh = ((const float4*)whp)[k4];
                const float4 xv = xp4[k4];
#pragma unroll
                for (int jj = 0; jj < 4; ++jj) {
                    const float hv = ws[FO_HT + ((k4 << 2) + jj) * 64 + lane];
                    acc += ((const float*)&wi)[jj] * ((const float*)&xv)[jj]
                         + ((const float*)&wh)[jj] * hv;
                }
            }
            gates_lds[w][lane] = acc;
            __syncthreads();

            // LSTM finalize: 128 threads = 2 cells x 64 batches
            if (tid < 128) {
                const int mloc = tid >> 6;       // 0..1
                const int b = tid & 63;
                float gv[4];
#pragma unroll
                for (int gi = 0; gi < 4; ++gi) {
                    const int jj = gi * 512 + bid * 2 + mloc;
                    gv[gi] = bih[jj] + bhh[jj] + gates_lds[gi * 2 + mloc][b];
                }
                const float ig = 1.f / (1.f + expf(-gv[0]));
                const float fg = 1.f / (1.f + expf(-gv[1]));
                const float gg = tanhf(gv[2]);
                const float og = 1.f / (1.f + expf(-gv[3]));
                const int m = bid * 2 + mloc;
                const float c_prev = ws[FO_CT + m * 64 + b];
                const float c_rnn = fg * c_prev + ig * gg;
                const float h_rnn = og * tanhf(c_rnn);
                ws[FO_CRT + m * 64 + b] = c_rnn;
                ws[FO_HRT + m * 64 + b] = h_rnn;
                // quad-packed for logits: [k4][b][4]
                ws[FO_HR4 + (m >> 2) * 256 + b * 4 + (m & 3)] = h_rnn;
            }
            if (bid == NBLK - 1 && t > 0 && tid >= 128 && tid < 192) {
                const int b = tid - 128;
                out[(size_t)STEPS * BV + (size_t)b * STEPS + (t - 1)] = (float)tok_s[b];
            }
        }
        grid.sync();

        // ========== PhaseB: logits (lane=batch, wave-uniform rows) + argmax + attention ==========
        unsigned long long best = 0;
        const float* __restrict__ hb4 = ws + FO_HR4;
        if (bid < 192) {
            const int mw = bid * 8 + w;          // 0..1535 -> rows [mw*32, mw*32+32)
            const int vbase = mw * 32;
            float* tile = &tile_lds[w][0][0];    // [32][65]
#pragma unroll 1
            for (int p = 0; p < 4; ++p) {
                const int v0 = vbase + p * 8;
                const float* __restrict__ Ep = E + (size_t)v0 * H;
                float acc[8];
#pragma unroll
                for (int r = 0; r < 8; ++r) acc[r] = 0.f;
#pragma unroll 2
                for (int k4 = 0; k4 < 128; ++k4) {
                    const float4 hv = *(const float4*)(hb4 + (k4 << 8) + (lane << 2));
#pragma unroll
                    for (int r = 0; r < 8; ++r) {
                        const float4 e = *(const float4*)(Ep + (size_t)r * H + (k4 << 2));
                        acc[r] += e.x * hv.x + e.y * hv.y + e.z * hv.z + e.w * hv.w;
                    }
                }
#pragma unroll
                for (int r = 0; r < 8; ++r) {
                    const float lv = acc[r] + fcb[v0 + r];
                    tile[(p * 8 + r) * 65 + lane] = lv;
                    const unsigned long long key =
                        (((unsigned long long)sortable_bits(lv)) << 32) |
                        (unsigned long long)(0xFFFFFFFFu - (unsigned)(v0 + r));
                    if (key > best) best = key;
                }
            }
            __syncthreads();
            // coalesced tiled store: 64 lanes cover 8 batches x 32 vocab as float4
            float* __restrict__ obase = out + (size_t)t * BV;
#pragma unroll
            for (int i = 0; i < 8; ++i) {
                const int idx = i * 64 + lane;   // 0..511
                const int b = idx >> 3;          // 0..63
                const int vg = idx & 7;          // 0..7 -> rows vg*4..vg*4+3
                const float4 st = make_float4(tile[(vg * 4 + 0) * 65 + b],
                                              tile[(vg * 4 + 1) * 65 + b],
                                              tile[(vg * 4 + 2) * 65 + b],
                                              tile[(vg * 4 + 3) * 65 + b]);
                *(float4*)(obase + (size_t)b * V + vbase + vg * 4) = st;
            }
        } else {
            // blocks 192..255: leftover rows 49152..49999 (2/wave) + attention (batch = bid-192)
            const int aw = (bid - 192) * 8 + w;      // 0..511
            const int v0 = 49152 + aw * 2;
            if (v0 < V) {
                float a0 = 0.f, a1 = 0.f;
                const float* __restrict__ Ep0 = E + (size_t)v0 * H;
                const float* __restrict__ Ep1 = E + (size_t)(v0 + 1) * H;
#pragma unroll 2
                for (int k4 = 0; k4 < 128; ++k4) {
                    const float4 hv = *(const float4*)(hb4 + (k4 << 8) + (lane << 2));
                    const float4 e0 = *(const float4*)(Ep0 + (k4 << 2));
                    const float4 e1 = *(const float4*)(Ep1 + (k4 << 2));
                    a0 += e0.x * hv.x + e0.y * hv.y + e0.z * hv.z + e0.w * hv.w;
                    a1 += e1.x * hv.x + e1.y * hv.y + e1.z * hv.z + e1.w * hv.w;
                }
                const float lv0 = a0 + fcb[v0];
                const float lv1 = a1 + fcb[v0 + 1];
                const unsigned long long k0 =
                    (((unsigned long long)sortable_bits(lv0)) << 32) |
                    (unsigned long long)(0xFFFFFFFFu - (unsigned)v0);
                const unsigned long long k1 =
                    (((unsigned long long)sortable_bits(lv1)) << 32) |
                    (unsigned long long)(0xFFFFFFFFu - (unsigned)(v0 + 1));
                best = (k0 > k1) ? k0 : k1;
                float* o = out + (size_t)t * BV + (size_t)lane * V + v0;
                *(float2*)o = make_float2(lv0, lv1);
            }
            // ---- attention for batch b = bid - 192 ----
            const int b = bid - 192;
            float hr8[8], cr8[8];
#pragma unroll
            for (int i = 0; i < 8; ++i) {
                const int k = lane * 8 + i;
                hr8[i] = ws[FO_HRT + k * 64 + b];
                cr8[i] = ws[FO_CRT + k * 64 + b];
            }
            const float scale = 0.044194173824159216f; // 1/sqrt(512)
            for (int s = w; s < S; s += 8) {
                const float* e = enc + ((size_t)s * B + b) * H + lane * 8;
                float dh = 0.f, dc = 0.f;
#pragma unroll
                for (int i = 0; i < 8; ++i) { const float ev = e[i]; dh += ev * hr8[i]; dc += ev * cr8[i]; }
#pragma unroll
                for (int off = 32; off; off >>= 1) { dh += __shfl_down(dh, off); dc += __shfl_down(dc, off); }
                if (lane == 0) { sc_h[s] = dh * scale; sc_c[s] = dc * scale; }
            }
            __syncthreads();
            if (w < 2) {
                float* sc = w ? sc_c : sc_h;
                float* a  = w ? a_c  : a_h;
                const float vval = (lane < S) ? sc[lane] : -__builtin_inff();
                float mx = vval;
#pragma unroll
                for (int off = 32; off; off >>= 1) mx = fmaxf(mx, __shfl_xor(mx, off));
                const float e = (lane < S) ? expf(vval - mx) : 0.f;
                float sum = e;
#pragma unroll
                for (int off = 32; off; off >>= 1) sum += __shfl_xor(sum, off);
                if (lane < S) a[lane] = e / sum;
            }
            __syncthreads();
            if (tid < 256) {
                const int kk = tid * 2;
                float ch0 = 0, ch1 = 0, cc0 = 0, cc1 = 0;
                for (int s = 0; s < S; ++s) {
                    const float2 e2 = *(const float2*)(enc + ((size_t)s * B + b) * H + kk);
                    const float ah = a_h[s], ac = a_c[s];
                    ch0 += ah * e2.x; ch1 += ah * e2.y;
                    cc0 += ac * e2.x; cc1 += ac * e2.y;
                }
                const float hr0 = ws[FO_HRT + kk * 64 + b], hr1 = ws[FO_HRT + (kk + 1) * 64 + b];
                const float cr0 = ws[FO_CRT + kk * 64 + b], cr1 = ws[FO_CRT + (kk + 1) * 64 + b];
                ws[FO_HT + kk * 64 + b]       = ch0 + hr0;
                ws[FO_HT + (kk + 1) * 64 + b] = ch1 + hr1;
                ws[FO_CT + kk * 64 + b]       = cc0 + cr0;
                ws[FO_CT + (kk + 1) * 64 + b] = cc1 + cr1;
            }
        }
        // ---- block-level argmax reduce -> per-block partial (plain store, no atomics) ----
        redbuf[w][lane] = best;
        __syncthreads();
        if (w == 0) {
            unsigned long long mm = redbuf[0][lane];
#pragma unroll
            for (int i = 1; i < 8; ++i) {
                const unsigned long long kk = redbuf[i][lane];
                if (kk > mm) mm = kk;
            }
            red[(size_t)bid * 64 + lane] = mm;
        }
        grid.sync();
    }
    // ---- epilogue: final step's tokens ----
    if (bid == NBLK - 1) {
        unsigned long long m = 0;
#pragma unroll 4
        for (int i = 0; i < 32; ++i) {
            const unsigned long long kk = red[(size_t)(w * 32 + i) * 64 + lane];
            if (kk > m) m = kk;
        }
        redbuf[w][lane] = m;
        __syncthreads();
        if (w == 0) {
            unsigned long long mm = redbuf[0][lane];
#pragma unroll
            for (int i = 1; i < 8; ++i) {
                const unsigned long long kk = redbuf[i][lane];
                if (kk > mm) mm = kk;
            }
            const int tk = (int)(0xFFFFFFFFu - (unsigned)(mm & 0xFFFFFFFFull));
            out[(size_t)STEPS * BV + (size_t)lane * STEPS + (STEPS - 1)] = (float)tk;
        }
    }
}

// =====================================================================
// Fallback: previous harness-verified 5-kernel path (used only if the
// cooperative launch is rejected by the runtime/capture).
// =====================================================================

__global__ __launch_bounds__(256) void k0_init(const float* __restrict__ E,
                                               const int* __restrict__ tok0,
                                               const float* __restrict__ h0,
                                               const float* __restrict__ c0,
                                               float* __restrict__ ws) {
    const int b = blockIdx.x;
    const int t = tok0[b];
    for (int k = threadIdx.x; k < H; k += 256) {
        ws[OFF_XT + k * 64 + b] = E[(size_t)t * H + k];
        ws[OFF_HT + k * 64 + b] = h0[b * H + k];
        ws[OFF_CT + k * 64 + b] = c0[b * H + k];
    }
}

__global__ __launch_bounds__(256) void k1_gates(const float* __restrict__ Wih,
                                                const float* __restrict__ Whh,
                                                float* __restrict__ ws) {
    const int tid = threadIdx.x;
    const int jt = blockIdx.x & 15;
    const int ks = blockIdx.x >> 4;
    const int jl = tid & 127;
    const int bg = __builtin_amdgcn_readfirstlane(tid >> 7);
    const int j = jt * 128 + jl;
    const int b0 = bg * 32;
    const float* __restrict__ xT = ws + OFF_XT;
    const float* __restrict__ hT = ws + OFF_HT;

    float acc[32];
#pragma unroll
    for (int i = 0; i < 32; i++) acc[i] = 0.f;

    const int k0 = ks * 64;
    const float4* wi4 = (const float4*)(Wih + (size_t)j * H + k0);
    const float4* wh4 = (const float4*)(Whh + (size_t)j * H + k0);
    for (int k4 = 0; k4 < 16; k4++) {
        float4 wi = wi4[k4];
        float4 wh = wh4[k4];
#pragma unroll
        for (int jj = 0; jj < 4; jj++) {
            const float wiv = ((const float*)&wi)[jj];
            const float whv = ((const float*)&wh)[jj];
            const int k = k0 + k4 * 4 + jj;
            const float* xr = xT + k * 64 + b0;
            const float* hr = hT + k * 64 + b0;
#pragma unroll
            for (int bb = 0; bb < 32; bb++)
                acc[bb] += wiv * xr[bb] + whv * hr[bb];
        }
    }
    float* outp = ws + OFF_GP + ((size_t)ks * G4 + j) * 64 + b0;
#pragma unroll
    for (int b4 = 0; b4 < 8; b4++)
        ((float4*)outp)[b4] = make_float4(acc[b4*4], acc[b4*4+1], acc[b4*4+2], acc[b4*4+3]);
}

__global__ __launch_bounds__(256) void k2_fin(const float* __restrict__ b_ih,
                                              const float* __restrict__ b_hh,
                                              float* __restrict__ ws) {
    const int tid = threadIdx.x;
    const int b = tid & 63;
    const int m = blockIdx.x * 4 + (tid >> 6);
    const float* __restrict__ gp = ws + OFF_GP;

    float g[4];
#pragma unroll
    for (int gi = 0; gi < 4; gi++) {
        const int j = gi * 512 + m;
        float s = b_ih[j] + b_hh[j];
#pragma unroll
        for (int ks = 0; ks < 8; ks++)
            s += gp[((size_t)ks * G4 + j) * 64 + b];
        g[gi] = s;
    }
    const float ig = 1.f / (1.f + expf(-g[0]));
    const float fg = 1.f / (1.f + expf(-g[1]));
    const float gg = tanhf(g[2]);
    const float og = 1.f / (1.f + expf(-g[3]));
    const float c_prev = ws[OFF_CT + m * 64 + b];
    const float c_rnn = fg * c_prev + ig * gg;
    const float h_rnn = og * tanhf(c_rnn);
    ws[OFF_CRT + m * 64 + b] = c_rnn;
    ws[OFF_HRT + m * 64 + b] = h_rnn;
}

__global__ __launch_bounds__(256) void k3_attn(const float* __restrict__ enc,
                                               float* __restrict__ ws) {
    const int b = blockIdx.x;
    const int tid = threadIdx.x;
    const int lane = tid & 63;
    const int wv = __builtin_amdgcn_readfirstlane(tid >> 6);

    __shared__ float sc_h[64], sc_c[64], a_h[64], a_c[64];

    float hr[8], cr[8];
#pragma unroll
    for (int i = 0; i < 8; i++) {
        const int k = lane * 8 + i;
        hr[i] = ws[OFF_HRT + k * 64 + b];
        cr[i] = ws[OFF_CRT + k * 64 + b];
    }
    const float scale = 0.044194173824159216f;
    for (int s = wv; s < S; s += 4) {
        const float* e = enc + ((size_t)s * B + b) * H + lane * 8;
        float dh = 0.f, dc = 0.f;
#pragma unroll
        for (int i = 0; i < 8; i++) {
            const float ev = e[i];
            dh += ev * hr[i];
            dc += ev * cr[i];
        }
#pragma unroll
        for (int off = 32; off; off >>= 1) {
            dh += __shfl_down(dh, off);
            dc += __shfl_down(dc, off);
        }
        if (lane == 0) { sc_h[s] = dh * scale; sc_c[s] = dc * scale; }
    }
    __syncthreads();
    if (wv < 2) {
        float* sc = wv ? sc_c : sc_h;
        float* a  = wv ? a_c  : a_h;
        float vval = (lane < S) ? sc[lane] : -__builtin_inff();
        float mx = vval;
#pragma unroll
        for (int off = 32; off; off >>= 1) mx = fmaxf(mx, __shfl_xor(mx, off));
        float e = (lane < S) ? expf(vval - mx) : 0.f;
        float sum = e;
#pragma unroll
        for (int off = 32; off; off >>= 1) sum += __shfl_xor(sum, off);
        if (lane < S) a[lane] = e / sum;
    }
    __syncthreads();
    {
        const int kk = tid * 2;
        float ch0 = 0, ch1 = 0, cc0 = 0, cc1 = 0;
        for (int s = 0; s < S; s++) {
            const float2 e2 = *(const float2*)(enc + ((size_t)s * B + b) * H + kk);
            const float ah = a_h[s], ac = a_c[s];
            ch0 += ah * e2.x; ch1 += ah * e2.y;
            cc0 += ac * e2.x; cc1 += ac * e2.y;
        }
        const float hr0 = ws[OFF_HRT + kk * 64 + b], hr1 = ws[OFF_HRT + (kk + 1) * 64 + b];
        const float cr0 = ws[OFF_CRT + kk * 64 + b], cr1 = ws[OFF_CRT + (kk + 1) * 64 + b];
        ws[OFF_HT + kk * 64 + b] = ch0 + hr0;
        ws[OFF_HT + (kk + 1) * 64 + b] = ch1 + hr1;
        ws[OFF_CT + kk * 64 + b] = cc0 + cr0;
        ws[OFF_CT + (kk + 1) * 64 + b] = cc1 + cr1;
    }
}

__global__ __launch_bounds__(256) void k4_logits(const float* __restrict__ E,
                                                 const float* __restrict__ fcb,
                                                 const float* __restrict__ ws,
                                                 float* __restrict__ out,
                                                 int step) {
    const int tid = threadIdx.x;
    const int vt = tid & 127;
    const int bg = __builtin_amdgcn_readfirstlane(tid >> 7);
    const int v = blockIdx.x * 128 + vt;
    const bool valid = v < V;
    const int vc = valid ? v : 0;
    const float* __restrict__ hT = ws + OFF_HRT + bg * 32;

    float acc[32];
#pragma unroll
    for (int i = 0; i < 32; i++) acc[i] = 0.f;

    const float4* e4 = (const float4*)(E + (size_t)vc * H);
    for (int k4 = 0; k4 < 128; k4++) {
        const float4 e = e4[k4];
#pragma unroll
        for (int jj = 0; jj < 4; jj++) {
            const float ev = ((const float*)&e)[jj];
            const float* __restrict__ h = hT + (k4 * 4 + jj) * 64;
#pragma unroll
            for (int bb = 0; bb < 32; bb++) acc[bb] += ev * h[bb];
        }
    }
    if (valid) {
        const float bias = fcb[v];
        float* o = out + (size_t)step * BV + (size_t)(bg * 32) * V + v;
#pragma unroll
        for (int bb = 0; bb < 32; bb++) o[(size_t)bb * V] = acc[bb] + bias;
    }
}

__global__ __launch_bounds__(256) void k5_argmax(const float* __restrict__ E,
                                                 float* __restrict__ ws,
                                                 float* __restrict__ out,
                                                 int step) {
    const int b = blockIdx.x;
    const int tid = threadIdx.x;
    const float* __restrict__ lg = out + (size_t)step * BV + (size_t)b * V;

    float best = -__builtin_inff();
    int bi = 0;
    for (int v = tid; v < V; v += 256) {
        const float x = lg[v];
        if (x > best) { best = x; bi = v; }
    }
#pragma unroll
    for (int off = 32; off; off >>= 1) {
        const float ov = __shfl_down(best, off);
        const int oi = __shfl_down(bi, off);
        if (ov > best || (ov == best && oi < bi)) { best = ov; bi = oi; }
    }
    __shared__ float wvv[4];
    __shared__ int wii[4];
    __shared__ int stok;
    const int lane = tid & 63, w = tid >> 6;
    if (lane == 0) { wvv[w] = best; wii[w] = bi; }
    __syncthreads();
    if (tid == 0) {
        float bv = wvv[0]; int bj = wii[0];
#pragma unroll
        for (int k = 1; k < 4; k++)
            if (wvv[k] > bv || (wvv[k] == bv && wii[k] < bj)) { bv = wvv[k]; bj = wii[k]; }
        stok = bj;
        ((int*)(ws + OFF_TOK))[b] = bj;
        out[(size_t)STEPS * BV + (size_t)b * STEPS + step] = (float)bj;
    }
    __syncthreads();
    const int t = stok;
    for (int k = tid; k < H; k += 256)
        ws[OFF_XT + k * 64 + b] = E[(size_t)t * H + k];
}

// =====================================================================

extern "C" void kernel_launch(void* const* d_in, const int* in_sizes, int n_in,
                              void* d_out, int out_size, void* d_ws, size_t ws_size,
                              hipStream_t stream) {
    (void)in_sizes; (void)n_in; (void)out_size; (void)ws_size;
    const float* E    = (const float*)d_in[0];
    const float* fcb  = (const float*)d_in[1];
    const float* Wih  = (const float*)d_in[2];
    const float* Whh  = (const float*)d_in[3];
    const float* bih  = (const float*)d_in[4];
    const float* bhh  = (const float*)d_in[5];
    const float* enc  = (const float*)d_in[6];
    const float* h0   = (const float*)d_in[7];
    const float* c0   = (const float*)d_in[8];
    const int*   tok0 = (const int*)d_in[9];
    float* out = (float*)d_out;
    float* ws  = (float*)d_ws;

    void* args[12] = { (void*)&E, (void*)&fcb, (void*)&Wih, (void*)&Whh,
                       (void*)&bih, (void*)&bhh, (void*)&enc, (void*)&h0,
                       (void*)&c0, (void*)&tok0, (void*)&out, (void*)&ws };

    hipError_t err = hipLaunchCooperativeKernel((const void*)kfused,
                                                dim3(NBLK), dim3(NTHR),
                                                args, 0, stream);
    if (err != hipSuccess) {
        // Fallback: previously verified multi-kernel path.
        k0_init<<<64, 256, 0, stream>>>(E, tok0, h0, c0, ws);
        for (int t = 0; t < STEPS; t++) {
            k1_gates<<<128, 256, 0, stream>>>(Wih, Whh, ws);
            k2_fin<<<128, 256, 0, stream>>>(bih, bhh, ws);
            k3_attn<<<64, 256, 0, stream>>>(enc, ws);
            k4_logits<<<391, 256, 0, stream>>>(E, fcb, ws, out, t);
            k5_argmax<<<64, 256, 0, stream>>>(E, ws, out, t);
        }
    }
}

// Round 8
// 8240.726 us; speedup vs baseline: 1.7033x; 1.4036x over previous
//
#include <hip/hip_runtime.h>
#include <hip/hip_cooperative_groups.h>
#include <math.h>

namespace cg = cooperative_groups;

#define H 512
#define V 50000
#define B 64
#define S 50
#define STEPS 31
#define NBLK 256
#define NTHR 512
#define G4 2048
static const size_t BV = (size_t)B * V;   // 3,200,000

// ---------------- fused-kernel workspace layout (floats) ----------------
#define FO_HT   0          // attended h state  [512][64]  (LSTM input h)
#define FO_CT   32768      // attended c state  [512][64]  (LSTM input c)
#define FO_HRT  65536      // pre-attention h_rnn [512][64] (attention/residual)
#define FO_CRT  98304      // pre-attention c_rnn [512][64]
#define FO_RED  131072     // per-block argmax partials: 256 blocks x 64 u64
#define FO_HR4  163840     // h_rnn quad-packed [128 k4][64 b][4] = 32768 floats

// ---------------- fallback (previous verified) ws layout ----------------
#define OFF_XT   0
#define OFF_HT   32768
#define OFF_CT   65536
#define OFF_HRT  98304
#define OFF_CRT  131072
#define OFF_TOK  163840
#define OFF_GP   163904

// =====================================================================
// Fused persistent cooperative kernel
// =====================================================================

__device__ __forceinline__ unsigned sortable_bits(float f) {
    unsigned u = __float_as_uint(f);
    return (u & 0x80000000u) ? ~u : (u | 0x80000000u);
}

__device__ __forceinline__ unsigned long long shfl_down_u64(unsigned long long x, int off) {
    const unsigned lo = __shfl_down((unsigned)x, off);
    const unsigned hi = __shfl_down((unsigned)(x >> 32), off);
    return (((unsigned long long)hi) << 32) | (unsigned long long)lo;
}

__global__ __launch_bounds__(NTHR, 1) void kfused(
    const float* __restrict__ E,   const float* __restrict__ fcb,
    const float* __restrict__ Wih, const float* __restrict__ Whh,
    const float* __restrict__ bih, const float* __restrict__ bhh,
    const float* __restrict__ enc, const float* __restrict__ h0,
    const float* __restrict__ c0,  const int* __restrict__ tok0,
    float* __restrict__ out,       float* __restrict__ ws)
{
    cg::grid_group grid = cg::this_grid();
    const int bid  = blockIdx.x;
    const int tid  = threadIdx.x;
    const int lane = tid & 63;
    const int w    = __builtin_amdgcn_readfirstlane(tid >> 6);  // wave 0..7
    unsigned long long* __restrict__ red = (unsigned long long*)(ws + FO_RED);

    // E chunk [256 row][68 stride] (pad 68 staggers banks: q=(l+k4l)%8, uniform),
    // h chunk [16 k4][64 b][4]
    __shared__ float elds[256 * 68];                // 69632 B
    __shared__ float hlds[4096];                    // 16384 B
    __shared__ float gates_lds[8][64];
    __shared__ unsigned long long redbuf[8][64];
    __shared__ int tok_s[64];
    __shared__ float sc_h[64], sc_c[64], a_h[64], a_c[64];

    // ---------------- P0: init state (verified R4) ----------------
    {
        const int g = bid * NTHR + tid;
        if (g < H * B) {
            const int k = g >> 6, b = g & 63;
            ws[FO_HT + k * 64 + b] = h0[(size_t)b * H + k];
            ws[FO_CT + k * 64 + b] = c0[(size_t)b * H + k];
        }
    }
    grid.sync();

    for (int t = 0; t < STEPS; ++t) {
        // ========== PhaseA (verified R4): token-reduce + gates/LSTM ==========
        if (t > 0) {
            unsigned long long m = 0;
#pragma unroll 4
            for (int i = 0; i < 32; ++i) {
                const unsigned long long kk = red[(size_t)(w * 32 + i) * 64 + lane];
                if (kk > m) m = kk;
            }
            redbuf[w][lane] = m;
            __syncthreads();
            if (w == 0) {
                unsigned long long mm = redbuf[0][lane];
#pragma unroll
                for (int i = 1; i < 8; ++i) {
                    const unsigned long long kk = redbuf[i][lane];
                    if (kk > mm) mm = kk;
                }
                tok_s[lane] = (int)(0xFFFFFFFFu - (unsigned)(mm & 0xFFFFFFFFull));
            }
            __syncthreads();
        }
        {
            // gates GEMV: block owns cells bid*2, bid*2+1; wave w -> row j
            const int tk = (t == 0) ? tok0[lane] : tok_s[lane];
            const int j = (w >> 1) * 512 + bid * 2 + (w & 1);
            const float* __restrict__ wip = Wih + (size_t)j * H;
            const float* __restrict__ whp = Whh + (size_t)j * H;
            const float4* __restrict__ xp4 = (const float4*)(E + (size_t)tk * H);
            float acc = 0.f;
#pragma unroll 2
            for (int k4 = 0; k4 < 128; ++k4) {
                const float4 wi = ((const float4*)wip)[k4];
                const float4 wh = ((const float4*)whp)[k4];
                const float4 xv = xp4[k4];
#pragma unroll
                for (int jj = 0; jj < 4; ++jj) {
                    const float hv = ws[FO_HT + ((k4 << 2) + jj) * 64 + lane];
                    acc += ((const float*)&wi)[jj] * ((const float*)&xv)[jj]
                         + ((const float*)&wh)[jj] * hv;
                }
            }
            gates_lds[w][lane] = acc;
            __syncthreads();

            // LSTM finalize: 128 threads = 2 cells x 64 batches
            if (tid < 128) {
                const int mloc = tid >> 6;       // 0..1
                const int b = tid & 63;
                float gv[4];
#pragma unroll
                for (int gi = 0; gi < 4; ++gi) {
                    const int jj = gi * 512 + bid * 2 + mloc;
                    gv[gi] = bih[jj] + bhh[jj] + gates_lds[gi * 2 + mloc][b];
                }
                const float ig = 1.f / (1.f + expf(-gv[0]));
                const float fg = 1.f / (1.f + expf(-gv[1]));
                const float gg = tanhf(gv[2]);
                const float og = 1.f / (1.f + expf(-gv[3]));
                const int m = bid * 2 + mloc;
                const float c_prev = ws[FO_CT + m * 64 + b];
                const float c_rnn = fg * c_prev + ig * gg;
                const float h_rnn = og * tanhf(c_rnn);
                ws[FO_CRT + m * 64 + b] = c_rnn;
                ws[FO_HRT + m * 64 + b] = h_rnn;
                ws[FO_HR4 + (m >> 2) * 256 + b * 4 + (m & 3)] = h_rnn;  // quad-packed
            }
            if (bid == NBLK - 1 && t > 0 && tid >= 128 && tid < 192) {
                const int b = tid - 128;
                out[(size_t)STEPS * BV + (size_t)b * STEPS + (t - 1)] = (float)tok_s[b];
            }
        }
        grid.sync();

        // ========== PhaseB: logits GEMM (reg-blocked, LDS-tiled) ==========
        if (bid < 192) {
            const int vbase = bid << 8;          // 256-row tile
            const int l = lane;
            float acc[4][8];
#pragma unroll
            for (int r = 0; r < 4; ++r)
#pragma unroll
                for (int bb = 0; bb < 8; ++bb) acc[r][bb] = 0.f;

            float4 stg[8], hstg[2];
            // prologue: chunk 0 staging loads (coalesced)
#pragma unroll
            for (int i = 0; i < 8; ++i) {
                const int f = tid + (i << 9);
                stg[i] = *(const float4*)(E + (size_t)(vbase + (f >> 4)) * 512 + ((f & 15) << 2));
            }
#pragma unroll
            for (int i = 0; i < 2; ++i)
                hstg[i] = *(const float4*)(ws + FO_HR4 + ((tid + (i << 9)) << 2));

#pragma unroll 1
            for (int c = 0; c < 8; ++c) {
                // write staged chunk to LDS (E row-major stride-68, h linear)
#pragma unroll
                for (int i = 0; i < 8; ++i) {
                    const int f = tid + (i << 9);
                    const int row = f >> 4, k4l = f & 15;
                    *(float4*)&elds[row * 68 + (k4l << 2)] = stg[i];
                }
#pragma unroll
                for (int i = 0; i < 2; ++i)
                    ((float4*)hlds)[tid + (i << 9)] = hstg[i];
                __syncthreads();
                // prefetch next chunk into regs (hides HBM under compute)
                if (c < 7) {
                    const int kofs = (c + 1) << 6;
#pragma unroll
                    for (int i = 0; i < 8; ++i) {
                        const int f = tid + (i << 9);
                        stg[i] = *(const float4*)(E + (size_t)(vbase + (f >> 4)) * 512 + kofs + ((f & 15) << 2));
                    }
#pragma unroll
                    for (int i = 0; i < 2; ++i)
                        hstg[i] = *(const float4*)(ws + FO_HR4 + ((c + 1) << 12) + ((tid + (i << 9)) << 2));
                }
                // compute 16 k4 of this chunk; lane l owns rows l+64s (s=0..3)
#pragma unroll 2
                for (int k4l = 0; k4l < 16; ++k4l) {
                    const float* eb = elds + l * 68 + (k4l << 2);
                    const float4 e0 = *(const float4*)(eb);
                    const float4 e1 = *(const float4*)(eb + 4352);
                    const float4 e2 = *(const float4*)(eb + 8704);
                    const float4 e3 = *(const float4*)(eb + 13056);
                    const float4* hb = (const float4*)(hlds + (k4l << 8) + (w << 5));
                    float4 hq[8];
#pragma unroll
                    for (int bb = 0; bb < 8; ++bb) hq[bb] = hb[bb];
#pragma unroll
                    for (int bb = 0; bb < 8; ++bb) {
                        const float4 h4 = hq[bb];
                        acc[0][bb] += e0.x*h4.x + e0.y*h4.y + e0.z*h4.z + e0.w*h4.w;
                        acc[1][bb] += e1.x*h4.x + e1.y*h4.y + e1.z*h4.z + e1.w*h4.w;
                        acc[2][bb] += e2.x*h4.x + e2.y*h4.y + e2.z*h4.z + e2.w*h4.w;
                        acc[3][bb] += e3.x*h4.x + e3.y*h4.y + e3.z*h4.z + e3.w*h4.w;
                    }
                }
                __syncthreads();
            }
            // epilogue: bias, coalesced dword stores, in-register argmax keys
            float bias_s[4];
#pragma unroll
            for (int s = 0; s < 4; ++s) bias_s[s] = fcb[vbase + l + (s << 6)];
            unsigned long long best8[8];
#pragma unroll
            for (int i = 0; i < 8; ++i) best8[i] = 0ull;
            float* ob = out + (size_t)t * BV + vbase + l;
#pragma unroll
            for (int bb = 0; bb < 8; ++bb) {
                float* obb = ob + (size_t)((w << 3) + bb) * V;
#pragma unroll
                for (int s = 0; s < 4; ++s) {
                    const float xv = acc[s][bb] + bias_s[s];
                    __builtin_nontemporal_store(xv, obb + (s << 6));
                    const int vi = vbase + l + (s << 6);
                    const unsigned long long key =
                        (((unsigned long long)sortable_bits(xv)) << 32) |
                        (unsigned long long)(0xFFFFFFFFu - (unsigned)vi);
                    if (key > best8[bb]) best8[bb] = key;
                }
            }
#pragma unroll
            for (int off = 32; off; off >>= 1) {
#pragma unroll
                for (int bb = 0; bb < 8; ++bb) {
                    const unsigned long long o2 = shfl_down_u64(best8[bb], off);
                    if (o2 > best8[bb]) best8[bb] = o2;
                }
            }
            if (lane == 0) {
#pragma unroll
                for (int bb = 0; bb < 8; ++bb)
                    red[(size_t)bid * 64 + (w << 3) + bb] = best8[bb];
            }
        } else {
            // ---- mini-tiles: blocks 192..244 cover rows 49152..49999 (16 each) ----
            if (bid <= 244) {
                const int vb = 49152 + (bid - 192) * 16;
                unsigned long long bkey = 0;
                const float* __restrict__ hb4 = ws + FO_HR4;
#pragma unroll
                for (int p = 0; p < 2; ++p) {
                    const int row = vb + p * 8 + w;          // wave-uniform
                    const float4* __restrict__ e4 = (const float4*)(E + ((size_t)row << 9));
                    float acc = 0.f;
#pragma unroll 4
                    for (int k4 = 0; k4 < 128; ++k4) {
                        const float4 ev = e4[k4];
                        const float4 hv = *(const float4*)(hb4 + (k4 << 8) + (lane << 2));
                        acc += ev.x*hv.x + ev.y*hv.y + ev.z*hv.z + ev.w*hv.w;
                    }
                    const float lv = acc + fcb[row];
                    __builtin_nontemporal_store(lv, out + (size_t)t * BV + (size_t)lane * V + row);
                    const unsigned long long key =
                        (((unsigned long long)sortable_bits(lv)) << 32) |
                        (unsigned long long)(0xFFFFFFFFu - (unsigned)row);
                    if (key > bkey) bkey = key;
                }
                redbuf[w][lane] = bkey;
                __syncthreads();
                if (w == 0) {
                    unsigned long long mm = redbuf[0][lane];
#pragma unroll
                    for (int i = 1; i < 8; ++i) {
                        const unsigned long long kk = redbuf[i][lane];
                        if (kk > mm) mm = kk;
                    }
                    red[(size_t)bid * 64 + lane] = mm;
                }
            } else {
                if (tid < 64) red[(size_t)bid * 64 + tid] = 0ull;   // no logits share
            }
            // ---- attention for batch b = bid - 192 (verified R4) ----
            const int b = bid - 192;
            float hr8[8], cr8[8];
#pragma unroll
            for (int i = 0; i < 8; ++i) {
                const int k = lane * 8 + i;
                hr8[i] = ws[FO_HRT + k * 64 + b];
                cr8[i] = ws[FO_CRT + k * 64 + b];
            }
            const float scale = 0.044194173824159216f; // 1/sqrt(512)
            for (int s = w; s < S; s += 8) {
                const float* e = enc + ((size_t)s * B + b) * H + lane * 8;
                float dh = 0.f, dc = 0.f;
#pragma unroll
                for (int i = 0; i < 8; ++i) { const float ev = e[i]; dh += ev * hr8[i]; dc += ev * cr8[i]; }
#pragma unroll
                for (int off = 32; off; off >>= 1) { dh += __shfl_down(dh, off); dc += __shfl_down(dc, off); }
                if (lane == 0) { sc_h[s] = dh * scale; sc_c[s] = dc * scale; }
            }
            __syncthreads();
            if (w < 2) {
                float* sc = w ? sc_c : sc_h;
                float* a  = w ? a_c  : a_h;
                const float vval = (lane < S) ? sc[lane] : -__builtin_inff();
                float mx = vval;
#pragma unroll
                for (int off = 32; off; off >>= 1) mx = fmaxf(mx, __shfl_xor(mx, off));
                const float e = (lane < S) ? expf(vval - mx) : 0.f;
                float sum = e;
#pragma unroll
                for (int off = 32; off; off >>= 1) sum += __shfl_xor(sum, off);
                if (lane < S) a[lane] = e / sum;
            }
            __syncthreads();
            if (tid < 256) {
                const int kk = tid * 2;
                float ch0 = 0, ch1 = 0, cc0 = 0, cc1 = 0;
                for (int s = 0; s < S; ++s) {
                    const float2 e2 = *(const float2*)(enc + ((size_t)s * B + b) * H + kk);
                    const float ah = a_h[s], ac = a_c[s];
                    ch0 += ah * e2.x; ch1 += ah * e2.y;
                    cc0 += ac * e2.x; cc1 += ac * e2.y;
                }
                const float hr0 = ws[FO_HRT + kk * 64 + b], hr1 = ws[FO_HRT + (kk + 1) * 64 + b];
                const float cr0 = ws[FO_CRT + kk * 64 + b], cr1 = ws[FO_CRT + (kk + 1) * 64 + b];
                ws[FO_HT + kk * 64 + b]       = ch0 + hr0;
                ws[FO_HT + (kk + 1) * 64 + b] = ch1 + hr1;
                ws[FO_CT + kk * 64 + b]       = cc0 + cr0;
                ws[FO_CT + (kk + 1) * 64 + b] = cc1 + cr1;
            }
        }
        grid.sync();
    }
    // ---- epilogue: final step's tokens (verified R4) ----
    if (bid == NBLK - 1) {
        unsigned long long m = 0;
#pragma unroll 4
        for (int i = 0; i < 32; ++i) {
            const unsigned long long kk = red[(size_t)(w * 32 + i) * 64 + lane];
            if (kk > m) m = kk;
        }
        redbuf[w][lane] = m;
        __syncthreads();
        if (w == 0) {
            unsigned long long mm = redbuf[0][lane];
#pragma unroll
            for (int i = 1; i < 8; ++i) {
                const unsigned long long kk = redbuf[i][lane];
                if (kk > mm) mm = kk;
            }
            const int tk = (int)(0xFFFFFFFFu - (unsigned)(mm & 0xFFFFFFFFull));
            out[(size_t)STEPS * BV + (size_t)lane * STEPS + (STEPS - 1)] = (float)tk;
        }
    }
}

// =====================================================================
// Fallback: previous harness-verified 5-kernel path (used only if the
// cooperative launch is rejected by the runtime/capture).
// =====================================================================

__global__ __launch_bounds__(256) void k0_init(const float* __restrict__ E,
                                               const int* __restrict__ tok0,
                                               const float* __restrict__ h0,
                                               const float* __restrict__ c0,
                                               float* __restrict__ ws) {
    const int b = blockIdx.x;
    const int t = tok0[b];
    for (int k = threadIdx.x; k < H; k += 256) {
        ws[OFF_XT + k * 64 + b] = E[(size_t)t * H + k];
        ws[OFF_HT + k * 64 + b] = h0[b * H + k];
        ws[OFF_CT + k * 64 + b] = c0[b * H + k];
    }
}

__global__ __launch_bounds__(256) void k1_gates(const float* __restrict__ Wih,
                                                const float* __restrict__ Whh,
                                                float* __restrict__ ws) {
    const int tid = threadIdx.x;
    const int jt = blockIdx.x & 15;
    const int ks = blockIdx.x >> 4;
    const int jl = tid & 127;
    const int bg = __builtin_amdgcn_readfirstlane(tid >> 7);
    const int j = jt * 128 + jl;
    const int b0 = bg * 32;
    const float* __restrict__ xT = ws + OFF_XT;
    const float* __restrict__ hT = ws + OFF_HT;

    float acc[32];
#pragma unroll
    for (int i = 0; i < 32; i++) acc[i] = 0.f;

    const int k0 = ks * 64;
    const float4* wi4 = (const float4*)(Wih + (size_t)j * H + k0);
    const float4* wh4 = (const float4*)(Whh + (size_t)j * H + k0);
    for (int k4 = 0; k4 < 16; k4++) {
        float4 wi = wi4[k4];
        float4 wh = wh4[k4];
#pragma unroll
        for (int jj = 0; jj < 4; jj++) {
            const float wiv = ((const float*)&wi)[jj];
            const float whv = ((const float*)&wh)[jj];
            const int k = k0 + k4 * 4 + jj;
            const float* xr = xT + k * 64 + b0;
            const float* hr = hT + k * 64 + b0;
#pragma unroll
            for (int bb = 0; bb < 32; bb++)
                acc[bb] += wiv * xr[bb] + whv * hr[bb];
        }
    }
    float* outp = ws + OFF_GP + ((size_t)ks * G4 + j) * 64 + b0;
#pragma unroll
    for (int b4 = 0; b4 < 8; b4++)
        ((float4*)outp)[b4] = make_float4(acc[b4*4], acc[b4*4+1], acc[b4*4+2], acc[b4*4+3]);
}

__global__ __launch_bounds__(256) void k2_fin(const float* __restrict__ b_ih,
                                              const float* __restrict__ b_hh,
                                              float* __restrict__ ws) {
    const int tid = threadIdx.x;
    const int b = tid & 63;
    const int m = blockIdx.x * 4 + (tid >> 6);
    const float* __restrict__ gp = ws + OFF_GP;

    float g[4];
#pragma unroll
    for (int gi = 0; gi < 4; gi++) {
        const int j = gi * 512 + m;
        float s = b_ih[j] + b_hh[j];
#pragma unroll
        for (int ks = 0; ks < 8; ks++)
            s += gp[((size_t)ks * G4 + j) * 64 + b];
        g[gi] = s;
    }
    const float ig = 1.f / (1.f + expf(-g[0]));
    const float fg = 1.f / (1.f + expf(-g[1]));
    const float gg = tanhf(g[2]);
    const float og = 1.f / (1.f + expf(-g[3]));
    const float c_prev = ws[OFF_CT + m * 64 + b];
    const float c_rnn = fg * c_prev + ig * gg;
    const float h_rnn = og * tanhf(c_rnn);
    ws[OFF_CRT + m * 64 + b] = c_rnn;
    ws[OFF_HRT + m * 64 + b] = h_rnn;
}

__global__ __launch_bounds__(256) void k3_attn(const float* __restrict__ enc,
                                               float* __restrict__ ws) {
    const int b = blockIdx.x;
    const int tid = threadIdx.x;
    const int lane = tid & 63;
    const int wv = __builtin_amdgcn_readfirstlane(tid >> 6);

    __shared__ float sc_h[64], sc_c[64], a_h[64], a_c[64];

    float hr[8], cr[8];
#pragma unroll
    for (int i = 0; i < 8; i++) {
        const int k = lane * 8 + i;
        hr[i] = ws[OFF_HRT + k * 64 + b];
        cr[i] = ws[OFF_CRT + k * 64 + b];
    }
    const float scale = 0.044194173824159216f;
    for (int s = wv; s < S; s += 4) {
        const float* e = enc + ((size_t)s * B + b) * H + lane * 8;
        float dh = 0.f, dc = 0.f;
#pragma unroll
        for (int i = 0; i < 8; i++) {
            const float ev = e[i];
            dh += ev * hr[i];
            dc += ev * cr[i];
        }
#pragma unroll
        for (int off = 32; off; off >>= 1) {
            dh += __shfl_down(dh, off);
            dc += __shfl_down(dc, off);
        }
        if (lane == 0) { sc_h[s] = dh * scale; sc_c[s] = dc * scale; }
    }
    __syncthreads();
    if (wv < 2) {
        float* sc = wv ? sc_c : sc_h;
        float* a  = wv ? a_c  : a_h;
        float vval = (lane < S) ? sc[lane] : -__builtin_inff();
        float mx = vval;
#pragma unroll
        for (int off = 32; off; off >>= 1) mx = fmaxf(mx, __shfl_xor(mx, off));
        float e = (lane < S) ? expf(vval - mx) : 0.f;
        float sum = e;
#pragma unroll
        for (int off = 32; off; off >>= 1) sum += __shfl_xor(sum, off);
        if (lane < S) a[lane] = e / sum;
    }
    __syncthreads();
    {
        const int kk = tid * 2;
        float ch0 = 0, ch1 = 0, cc0 = 0, cc1 = 0;
        for (int s = 0; s < S; s++) {
            const float2 e2 = *(const float2*)(enc + ((size_t)s * B + b) * H + kk);
            const float ah = a_h[s], ac = a_c[s];
            ch0 += ah * e2.x; ch1 += ah * e2.y;
            cc0 += ac * e2.x; cc1 += ac * e2.y;
        }
        const float hr0 = ws[OFF_HRT + kk * 64 + b], hr1 = ws[OFF_HRT + (kk + 1) * 64 + b];
        const float cr0 = ws[OFF_CRT + kk * 64 + b], cr1 = ws[OFF_CRT + (kk + 1) * 64 + b];
        ws[OFF_HT + kk * 64 + b] = ch0 + hr0;
        ws[OFF_HT + (kk + 1) * 64 + b] = ch1 + hr1;
        ws[OFF_CT + kk * 64 + b] = cc0 + cr0;
        ws[OFF_CT + (kk + 1) * 64 + b] = cc1 + cr1;
    }
}

__global__ __launch_bounds__(256) void k4_logits(const float* __restrict__ E,
                                                 const float* __restrict__ fcb,
                                                 const float* __restrict__ ws,
                                                 float* __restrict__ out,
                                                 int step) {
    const int tid = threadIdx.x;
    const int vt = tid & 127;
    const int bg = __builtin_amdgcn_readfirstlane(tid >> 7);
    const int v = blockIdx.x * 128 + vt;
    const bool valid = v < V;
    const int vc = valid ? v : 0;
    const float* __restrict__ hT = ws + OFF_HRT + bg * 32;

    float acc[32];
#pragma unroll
    for (int i = 0; i < 32; i++) acc[i] = 0.f;

    const float4* e4 = (const float4*)(E + (size_t)vc * H);
    for (int k4 = 0; k4 < 128; k4++) {
        const float4 e = e4[k4];
#pragma unroll
        for (int jj = 0; jj < 4; jj++) {
            const float ev = ((const float*)&e)[jj];
            const float* __restrict__ h = hT + (k4 * 4 + jj) * 64;
#pragma unroll
            for (int bb = 0; bb < 32; bb++) acc[bb] += ev * h[bb];
        }
    }
    if (valid) {
        const float bias = fcb[v];
        float* o = out + (size_t)step * BV + (size_t)(bg * 32) * V + v;
#pragma unroll
        for (int bb = 0; bb < 32; bb++) o[(size_t)bb * V] = acc[bb] + bias;
    }
}

__global__ __launch_bounds__(256) void k5_argmax(const float* __restrict__ E,
                                                 float* __restrict__ ws,
                                                 float* __restrict__ out,
                                                 int step) {
    const int b = blockIdx.x;
    const int tid = threadIdx.x;
    const float* __restrict__ lg = out + (size_t)step * BV + (size_t)b * V;

    float best = -__builtin_inff();
    int bi = 0;
    for (int v = tid; v < V; v += 256) {
        const float x = lg[v];
        if (x > best) { best = x; bi = v; }
    }
#pragma unroll
    for (int off = 32; off; off >>= 1) {
        const float ov = __shfl_down(best, off);
        const int oi = __shfl_down(bi, off);
        if (ov > best || (ov == best && oi < bi)) { best = ov; bi = oi; }
    }
    __shared__ float wvv[4];
    __shared__ int wii[4];
    __shared__ int stok;
    const int lane = tid & 63, w = tid >> 6;
    if (lane == 0) { wvv[w] = best; wii[w] = bi; }
    __syncthreads();
    if (tid == 0) {
        float bv = wvv[0]; int bj = wii[0];
#pragma unroll
        for (int k = 1; k < 4; k++)
            if (wvv[k] > bv || (wvv[k] == bv && wii[k] < bj)) { bv = wvv[k]; bj = wii[k]; }
        stok = bj;
        ((int*)(ws + OFF_TOK))[b] = bj;
        out[(size_t)STEPS * BV + (size_t)b * STEPS + step] = (float)bj;
    }
    __syncthreads();
    const int t = stok;
    for (int k = tid; k < H; k += 256)
        ws[OFF_XT + k * 64 + b] = E[(size_t)t * H + k];
}

// =====================================================================

extern "C" void kernel_launch(void* const* d_in, const int* in_sizes, int n_in,
                              void* d_out, int out_size, void* d_ws, size_t ws_size,
                              hipStream_t stream) {
    (void)in_sizes; (void)n_in; (void)out_size; (void)ws_size;
    const float* E    = (const float*)d_in[0];
    const float* fcb  = (const float*)d_in[1];
    const float* Wih  = (const float*)d_in[2];
    const float* Whh  = (const float*)d_in[3];
    const float* bih  = (const float*)d_in[4];
    const float* bhh  = (const float*)d_in[5];
    const float* enc  = (const float*)d_in[6];
    const float* h0   = (const float*)d_in[7];
    const float* c0   = (const float*)d_in[8];
    const int*   tok0 = (const int*)d_in[9];
    float* out = (float*)d_out;
    float* ws  = (float*)d_ws;

    void* args[12] = { (void*)&E, (void*)&fcb, (void*)&Wih, (void*)&Whh,
                       (void*)&bih, (void*)&bhh, (void*)&enc, (void*)&h0,
                       (void*)&c0, (void*)&tok0, (void*)&out, (void*)&ws };

    hipError_t err = hipLaunchCooperativeKernel((const void*)kfused,
                                                dim3(NBLK), dim3(NTHR),
                                                args, 0, stream);
    if (err != hipSuccess) {
        // Fallback: previously verified multi-kernel path.
        k0_init<<<64, 256, 0, stream>>>(E, tok0, h0, c0, ws);
        for (int t = 0; t < STEPS; t++) {
            k1_gates<<<128, 256, 0, stream>>>(Wih, Whh, ws);
            k2_fin<<<128, 256, 0, stream>>>(bih, bhh, ws);
            k3_attn<<<64, 256, 0, stream>>>(enc, ws);
            k4_logits<<<391, 256, 0, stream>>>(E, fcb, ws, out, t);
            k5_argmax<<<64, 256, 0, stream>>>(E, ws, out, t);
        }
    }
}